// Round 11
// baseline (301.446 us; speedup 1.0000x reference)
//
#include <hip/hip_runtime.h>
#include <hip/hip_bf16.h>

typedef float  f32x4  __attribute__((ext_vector_type(4)));
typedef __bf16 bf16x8 __attribute__((ext_vector_type(8)));

#define SCALE_QK 0.17677669529663687f  /* 32^-0.5 (reference uses DIM_HEAD) */

// B=131072, L=4, dim=256, inner=32, heads=4, dh=8
// rows = 524288 ; 16-row tiles = 32768 ; grid 1024 x 4 waves x 8 tiles
// JOURNAL:
//  - VGPR cap law (validated arg=1..4): cap = 256/(2nd launch_bounds arg).
//    (256,1) -> cap 256, no spill at natural ~190: r9 = 232us (best).
//  - vmcnt is ONE in-order counter: keep per-tile vmem = x-loads + stores ONLY.
//  - Swapped GEMM2 (bias-as-C, float4 stores): WRITE = 524MB exact (no write-amp).
//  - Occupancy pinned at 8 waves/CU (LDS 72KiB -> 2 blocks/CU; VGPR>128 -> 2/SIMD).
//  - r10: grid 512 (1 generation) REGRESSED 232->244: backfill load-balancing
//    beats prologue amortization. Keep grid 1024 (2 generations).
//  - r11: NT loads on x, NT stores on out (stream-through L2, no allocate) --
//    x and out are touch-once streams that otherwise thrash the 4MiB/XCD L2.

template<int CTRL>
__device__ __forceinline__ float dpp_add(float x) {
  int xi = __builtin_bit_cast(int, x);
  int yi = __builtin_amdgcn_mov_dpp(xi, CTRL, 0xF, 0xF, true);
  return x + __builtin_bit_cast(float, yi);
}

// ---------- prekernel: pack frag-ordered bf16 weights into d_ws ----------
// item = f*64 + lane, f in [0,64): wsf[item*8 + j]
// f in [0,48): GEMM1 frag (kt=f/6, ct=f%6): col n=ct*16+c, k=kt*32+g*8+j
// f in [48,64): Wo frag ct=f-48: col n=ct*16+c, k=g*8+j
__global__ void pack_weights(const float* __restrict__ Wq, const float* __restrict__ Wkv,
                             const float* __restrict__ Wo, __bf16* __restrict__ wsf) {
  const int item = blockIdx.x * 256 + threadIdx.x;   // 4096 items
  const int f = item >> 6, lane = item & 63;
  const int g = lane >> 4, c = lane & 15;
  union { bf16x8 v; __bf16 h[8]; } vv;
  if (f < 48) {
    const int kt = f / 6, ct = f - kt * 6;
    const int n = ct * 16 + c;
    #pragma unroll
    for (int j = 0; j < 8; ++j) {
      const int k = kt * 32 + g * 8 + j;
      vv.h[j] = (__bf16)((n < 32) ? Wq[k * 32 + n] : Wkv[k * 64 + (n - 32)]);
    }
  } else {
    const int ct = f - 48;
    const int n = ct * 16 + c;
    #pragma unroll
    for (int j = 0; j < 8; ++j) vv.h[j] = (__bf16)Wo[(g * 8 + j) * 256 + n];
  }
  *(bf16x8*)&wsf[item * 8] = vv.v;
}

#define FR(f) (*(const bf16x8*)&wfrag[(f)][lane][0])
#define MFMA(a, b, cc) __builtin_amdgcn_mfma_f32_16x16x32_bf16((a), (b), (cc), 0, 0, 0)

__global__ __launch_bounds__(256, 1) void fused_stattn(
    const float* __restrict__ x, const __bf16* __restrict__ wsf,
    const float* __restrict__ bo, const float* __restrict__ pe,
    float* __restrict__ out) {
  __shared__ __align__(16) __bf16 wfrag[64][64][8];   // 64 KiB (all frags)
  __shared__ __align__(16) __bf16 ao_lds[4][16][40];  // per-wave bounce
  __shared__ __align__(16) float bo_lds[256];
  __shared__ float pe_lds[64];

  const int tid  = threadIdx.x;
  const int lane = tid & 63;
  const int wv   = tid >> 6;
  const int g    = lane >> 4;   // 16-lane group
  const int c    = lane & 15;   // col within fragment / A-row

  const int slot  = blockIdx.x * 4 + wv;      // 0..4095
  const int tile0 = slot * 8;
  const f32x4* xv = (const f32x4*)x;          // row stride = 64 float4s

  // ---- tile0 x-burst FIRST: flies under the weight staging + barrier ----
  f32x4 xbuf[16];
  {
    const int base = (tile0 * 16 + c) * 64 + g * 2;
    #pragma unroll
    for (int kt = 0; kt < 8; ++kt) {
      xbuf[2*kt]   = __builtin_nontemporal_load(&xv[base + kt*8]);
      xbuf[2*kt+1] = __builtin_nontemporal_load(&xv[base + kt*8 + 1]);
    }
  }

  // prologue: packed weights ws -> LDS (4096 x 16B chunks), bo, pe
  #pragma unroll
  for (int it = 0; it < 16; ++it) {
    const int idx = it * 256 + tid;
    *(bf16x8*)&wfrag[0][0][idx * 8] = *(const bf16x8*)&wsf[idx * 8];
  }
  bo_lds[tid] = bo[tid];
  if (tid < 64) pe_lds[tid] = pe[tid];
  __syncthreads();

  // ---------------- main loop: 8 tiles per wave ----------------
  for (int t = 0; t < 8; ++t) {
    const int tile  = tile0 + t;
    const int ntile = (tile + 1 < 32768) ? tile + 1 : tile;   // clamp last global tile
    const int nbase = (ntile * 16 + c) * 64 + g * 2;

    // ---- GEMM1: x[16x256] @ Wqkv[256x96]; interleaved next-tile x prefetch ----
    f32x4 acc0 = {0,0,0,0}, acc1 = {0,0,0,0}, acc2 = {0,0,0,0};
    f32x4 acc3 = {0,0,0,0}, acc4 = {0,0,0,0}, acc5 = {0,0,0,0};
    #pragma unroll
    for (int kt = 0; kt < 8; ++kt) {
      union { bf16x8 v; __bf16 h[8]; } af;    // A-frag: row=c, k = kt*32 + g*8 + j
      #pragma unroll
      for (int j = 0; j < 4; ++j) {
        af.h[j]   = (__bf16)xbuf[2*kt][j];
        af.h[4+j] = (__bf16)xbuf[2*kt+1][j];
      }
      // prefetch next tile's k-slab into the just-consumed slots
      xbuf[2*kt]   = __builtin_nontemporal_load(&xv[nbase + kt*8]);
      xbuf[2*kt+1] = __builtin_nontemporal_load(&xv[nbase + kt*8 + 1]);

      acc0 = MFMA(af.v, FR(kt*6+0), acc0);
      acc1 = MFMA(af.v, FR(kt*6+1), acc1);
      acc2 = MFMA(af.v, FR(kt*6+2), acc2);
      acc3 = MFMA(af.v, FR(kt*6+3), acc3);
      acc4 = MFMA(af.v, FR(kt*6+4), acc4);
      acc5 = MFMA(af.v, FR(kt*6+5), acc5);
    }
    // C layout: lane(g,c) reg i -> row g*4+i (batch g, seq i), col c. q/k/v pairs.

    // ---- attention (in registers; 8-lane head-dim reduce via DPP) ----
    const int h0 = c >> 3;
    float ao0[4], ao1[4];
    #pragma unroll
    for (int p = 0; p < 2; ++p) {
      const f32x4 qa = p ? acc1 : acc0;
      const f32x4 ka = p ? acc3 : acc2;
      const f32x4 va = p ? acc5 : acc4;
      const int ph = 2 * p + h0;              // head owning cols p*16 + c
      float sim[4][4];
      #pragma unroll
      for (int i = 0; i < 4; ++i)
        #pragma unroll
        for (int j = 0; j < 4; ++j) {
          float pr = qa[i] * ka[j];
          pr = dpp_add<0xB1>(pr);             // quad_perm xor1
          pr = dpp_add<0x4E>(pr);             // quad_perm xor2
          pr = dpp_add<0x141>(pr);            // row_half_mirror
          sim[i][j] = pr * SCALE_QK + pe_lds[ph * 16 + i * 4 + j];
        }
      #pragma unroll
      for (int i = 0; i < 4; ++i) {
        const float m = fmaxf(fmaxf(sim[i][0], sim[i][1]), fmaxf(sim[i][2], sim[i][3]));
        const float e0 = __expf(sim[i][0] - m), e1 = __expf(sim[i][1] - m);
        const float e2 = __expf(sim[i][2] - m), e3 = __expf(sim[i][3] - m);
        const float rs = 1.0f / (e0 + e1 + e2 + e3);
        const float o  = (e0*va[0] + e1*va[1] + e2*va[2] + e3*va[3]) * rs;
        if (p) ao1[i] = o; else ao0[i] = o;
      }
    }

    // ---- bounce C-layout -> B-frag layout for GEMM2 (per-wave private) ----
    #pragma unroll
    for (int i = 0; i < 4; ++i) {
      ao_lds[wv][g*4 + i][c]      = (__bf16)ao0[i];
      ao_lds[wv][g*4 + i][16 + c] = (__bf16)ao1[i];
    }
    const bf16x8 a2 = *(const bf16x8*)&ao_lds[wv][c][g * 8];  // col=c(=x-row), k=g*8+j

    // ---- GEMM2 (swapped): Wo^T @ ao^T, bias as C-input, NT float4 stores ----
    // D: lane(g,c) reg i -> out col ct*16 + g*4 + i, x-row c.
    const int orow = (tile * 16 + c) * 256;
    #pragma unroll
    for (int ct = 0; ct < 16; ++ct) {
      const f32x4 bv = *(const f32x4*)&bo_lds[ct * 16 + g * 4];
      f32x4 o = MFMA(FR(48 + ct), a2, bv);
      __builtin_nontemporal_store(o, (f32x4*)&out[orow + ct * 16 + g * 4]);
    }
  }
}

extern "C" void kernel_launch(void* const* d_in, const int* in_sizes, int n_in,
                              void* d_out, int out_size, void* d_ws, size_t ws_size,
                              hipStream_t stream) {
  const float* x   = (const float*)d_in[0];
  const float* Wq  = (const float*)d_in[1];
  const float* Wkv = (const float*)d_in[2];
  const float* Wo  = (const float*)d_in[3];
  const float* bo  = (const float*)d_in[4];
  const float* pe  = (const float*)d_in[5];
  float* out = (float*)d_out;
  __bf16* wsf = (__bf16*)d_ws;   // 64 KiB of frag-ordered bf16 weights

  hipLaunchKernelGGL(pack_weights, dim3(16), dim3(256), 0, stream, Wq, Wkv, Wo, wsf);
  hipLaunchKernelGGL(fused_stattn, dim3(1024), dim3(256), 0, stream,
                     x, wsf, bo, pe, out);
}

// Round 12
// 230.470 us; speedup vs baseline: 1.3080x; 1.3080x over previous
//
#include <hip/hip_runtime.h>
#include <hip/hip_bf16.h>

typedef float  f32x4  __attribute__((ext_vector_type(4)));
typedef __bf16 bf16x8 __attribute__((ext_vector_type(8)));

#define SCALE_QK 0.17677669529663687f  /* 32^-0.5 (reference uses DIM_HEAD) */

// B=131072, L=4, dim=256, inner=32, heads=4, dh=8
// rows = 524288 ; 16-row tiles = 32768 ; grid 256 x 4 waves x 32 tiles
// JOURNAL:
//  - VGPR cap law: cap = 256/(2nd launch_bounds arg); exceed -> spill.
//  - vmcnt in-order: per-tile vmem must be x-loads + stores ONLY (weights in LDS).
//  - r10: 1-gen grid regressed (backfill balancing) -- but that was 2-block/CU;
//    here 1 block/CU + uniform work -> single gen OK.
//  - r11: NT loads/stores REGRESSED 232->301 (lost L3 residency). Reverted.
//  - r12 theory: TCP transaction fragmentation. Register-direct frag loads =
//    64 scattered 16B reqs/instr; swapped-GEMM2 stores = 16x64B/instr. Fix:
//    LDS-bounce both sides -> every global instr = contiguous 1KB.
//    Stage x via global_load_lds; D bounced through the consumed stage buffer.

template<int CTRL>
__device__ __forceinline__ float dpp_add(float x) {
  int xi = __builtin_bit_cast(int, x);
  int yi = __builtin_amdgcn_mov_dpp(xi, CTRL, 0xF, 0xF, true);
  return x + __builtin_bit_cast(float, yi);
}

// ---------- prekernel: pack frag-ordered bf16 weights into d_ws ----------
// item = f*64 + lane, f in [0,64): wsf[item*8 + j]
// f in [0,48): GEMM1 frag (kt=f/6, ct=f%6): col n=ct*16+c, k=kt*32+g*8+j
// f in [48,64): Wo frag ct=f-48: col n=ct*16+c, k=g*8+j
__global__ void pack_weights(const float* __restrict__ Wq, const float* __restrict__ Wkv,
                             const float* __restrict__ Wo, __bf16* __restrict__ wsf) {
  const int item = blockIdx.x * 256 + threadIdx.x;   // 4096 items
  const int f = item >> 6, lane = item & 63;
  const int g = lane >> 4, c = lane & 15;
  union { bf16x8 v; __bf16 h[8]; } vv;
  if (f < 48) {
    const int kt = f / 6, ct = f - kt * 6;
    const int n = ct * 16 + c;
    #pragma unroll
    for (int j = 0; j < 8; ++j) {
      const int k = kt * 32 + g * 8 + j;
      vv.h[j] = (__bf16)((n < 32) ? Wq[k * 32 + n] : Wkv[k * 64 + (n - 32)]);
    }
  } else {
    const int ct = f - 48;
    const int n = ct * 16 + c;
    #pragma unroll
    for (int j = 0; j < 8; ++j) vv.h[j] = (__bf16)Wo[(g * 8 + j) * 256 + n];
  }
  *(bf16x8*)&wsf[item * 8] = vv.v;
}

#define FR(f) (*(const bf16x8*)&wfrag[(f) * 512 + lane * 8])
#define MFMA(a, b, cc) __builtin_amdgcn_mfma_f32_16x16x32_bf16((a), (b), (cc), 0, 0, 0)

// LDS map (bytes):
//   [0, 65536)        wfrag: frag f at f*1024 + lane*16
//   [65536, 132096)   x stage / D bounce: wave wv at 65536 + wv*16640; row r at +r*1040
//   [132096, 137216)  ao bounce: wave wv at +wv*1280 ([16][40] bf16)
//   [137216, 138240)  bo (256 f32)
//   [138240, 138496)  pe (64 f32)
#define LDS_TOTAL 138496

__global__ __launch_bounds__(256, 1) void fused_stattn(
    const float* __restrict__ x, const __bf16* __restrict__ wsf,
    const float* __restrict__ bo, const float* __restrict__ pe,
    float* __restrict__ out) {
  extern __shared__ char smem[];

  const int tid  = threadIdx.x;
  const int lane = tid & 63;
  const int wv   = tid >> 6;
  const int g    = lane >> 4;   // 16-lane group
  const int c    = lane & 15;   // col within fragment / A-row

  __bf16* wfrag = (__bf16*)smem;
  char*   stg   = smem + 65536 + wv * 16640;           // wave-private stage/bounce
  __bf16* aoW   = (__bf16*)(smem + 132096 + wv * 1280);
  float*  bo_l  = (float*)(smem + 137216);
  float*  pe_l  = (float*)(smem + 138240);

  // prologue: packed weights ws -> LDS (4096 x 16B chunks), bo, pe
  #pragma unroll
  for (int it = 0; it < 16; ++it) {
    const int idx = it * 256 + tid;
    *(bf16x8*)&wfrag[idx * 8] = *(const bf16x8*)&wsf[idx * 8];
  }
  bo_l[tid] = bo[tid];
  if (tid < 64) pe_l[tid] = pe[tid];
  __syncthreads();

  const unsigned stg_lds = (unsigned)(unsigned long long)(void*)stg;  // LDS byte addr

  const int slot  = blockIdx.x * 4 + wv;      // 0..1023
  const int tile0 = slot * 32;                // 32 tiles per wave

  for (int t = 0; t < 32; ++t) {
    const int tile = tile0 + t;

    // ---- make sure last tile's store-reads are done, then stage this tile:
    //      16 x global_load_lds, each = 64 lanes x 16B = one contiguous 1KB row ----
    asm volatile("s_waitcnt lgkmcnt(0)" ::: "memory");
    {
      const float* src = x + (size_t)tile * 4096 + (lane << 2);
      #pragma unroll
      for (int r = 0; r < 16; ++r) {
        __builtin_amdgcn_global_load_lds(
            (const __attribute__((address_space(1))) void*)(src + r * 256),
            (__attribute__((address_space(3))) void*)(unsigned long long)(stg_lds + r * 1040),
            16, 0, 0);
      }
    }
    asm volatile("s_waitcnt vmcnt(0)" ::: "memory");   // staged (also drains old stores)
    __builtin_amdgcn_sched_barrier(0);                 // rule 18: pin ds_reads below wait

    // ---- GEMM1: x[16x256] @ Wqkv[256x96]; A-frags from LDS stage ----
    f32x4 acc0 = {0,0,0,0}, acc1 = {0,0,0,0}, acc2 = {0,0,0,0};
    f32x4 acc3 = {0,0,0,0}, acc4 = {0,0,0,0}, acc5 = {0,0,0,0};
    #pragma unroll
    for (int kt = 0; kt < 8; ++kt) {
      const f32x4 va = *(const f32x4*)(stg + c * 1040 + kt * 128 + g * 32);
      const f32x4 vb = *(const f32x4*)(stg + c * 1040 + kt * 128 + g * 32 + 16);
      union { bf16x8 v; __bf16 h[8]; } af;    // A-frag: row=c, k = kt*32 + g*8 + j
      #pragma unroll
      for (int j = 0; j < 4; ++j) { af.h[j] = (__bf16)va[j]; af.h[4+j] = (__bf16)vb[j]; }
      acc0 = MFMA(af.v, FR(kt*6+0), acc0);
      acc1 = MFMA(af.v, FR(kt*6+1), acc1);
      acc2 = MFMA(af.v, FR(kt*6+2), acc2);
      acc3 = MFMA(af.v, FR(kt*6+3), acc3);
      acc4 = MFMA(af.v, FR(kt*6+4), acc4);
      acc5 = MFMA(af.v, FR(kt*6+5), acc5);
    }
    // C layout: lane(g,c) reg i -> row g*4+i (batch g, seq i), col c. q/k/v pairs.

    // ---- attention (in registers; 8-lane head-dim reduce via DPP) ----
    const int h0 = c >> 3;
    float ao0[4], ao1[4];
    #pragma unroll
    for (int p = 0; p < 2; ++p) {
      const f32x4 qa = p ? acc1 : acc0;
      const f32x4 ka = p ? acc3 : acc2;
      const f32x4 va = p ? acc5 : acc4;
      const int ph = 2 * p + h0;              // head owning cols p*16 + c
      float sim[4][4];
      #pragma unroll
      for (int i = 0; i < 4; ++i)
        #pragma unroll
        for (int j = 0; j < 4; ++j) {
          float pr = qa[i] * ka[j];
          pr = dpp_add<0xB1>(pr);             // quad_perm xor1
          pr = dpp_add<0x4E>(pr);             // quad_perm xor2
          pr = dpp_add<0x141>(pr);            // row_half_mirror
          sim[i][j] = pr * SCALE_QK + pe_l[ph * 16 + i * 4 + j];
        }
      #pragma unroll
      for (int i = 0; i < 4; ++i) {
        const float m = fmaxf(fmaxf(sim[i][0], sim[i][1]), fmaxf(sim[i][2], sim[i][3]));
        const float e0 = __expf(sim[i][0] - m), e1 = __expf(sim[i][1] - m);
        const float e2 = __expf(sim[i][2] - m), e3 = __expf(sim[i][3] - m);
        const float rs = 1.0f / (e0 + e1 + e2 + e3);
        const float o  = (e0*va[0] + e1*va[1] + e2*va[2] + e3*va[3]) * rs;
        if (p) ao1[i] = o; else ao0[i] = o;
      }
    }

    // ---- bounce C-layout -> B-frag layout for GEMM2 (per-wave private) ----
    #pragma unroll
    for (int i = 0; i < 4; ++i) {
      aoW[(g*4 + i) * 40 + c]      = (__bf16)ao0[i];
      aoW[(g*4 + i) * 40 + 16 + c] = (__bf16)ao1[i];
    }
    const bf16x8 a2 = *(const bf16x8*)&aoW[c * 40 + g * 8];  // col=c(=x-row), k=g*8+j

    // ---- GEMM2 (swapped): Wo^T @ ao^T, bias as C-input; D into stage buffer
    //      (x fully consumed by this wave; wave-private -> no barrier) ----
    #pragma unroll
    for (int ct = 0; ct < 16; ++ct) {
      const f32x4 bv = *(const f32x4*)&bo_l[ct * 16 + g * 4];
      f32x4 o = MFMA(FR(48 + ct), a2, bv);
      // D: lane(g,c) reg i -> out row c, col ct*16 + g*4 + i
      *(f32x4*)(stg + c * 1040 + ct * 64 + g * 16) = o;
    }

    // ---- contiguous stores: row r = 64 lanes x 16B = 1KB per instr ----
    {
      float* orow = out + (size_t)tile * 4096 + (lane << 2);
      #pragma unroll
      for (int r = 0; r < 16; ++r) {
        const f32x4 v = *(const f32x4*)(stg + r * 1040 + lane * 16);
        *(f32x4*)(orow + r * 256) = v;
      }
    }
  }
}

extern "C" void kernel_launch(void* const* d_in, const int* in_sizes, int n_in,
                              void* d_out, int out_size, void* d_ws, size_t ws_size,
                              hipStream_t stream) {
  const float* x   = (const float*)d_in[0];
  const float* Wq  = (const float*)d_in[1];
  const float* Wkv = (const float*)d_in[2];
  const float* Wo  = (const float*)d_in[3];
  const float* bo  = (const float*)d_in[4];
  const float* pe  = (const float*)d_in[5];
  float* out = (float*)d_out;
  __bf16* wsf = (__bf16*)d_ws;   // 64 KiB of frag-ordered bf16 weights

  (void)hipFuncSetAttribute(reinterpret_cast<const void*>(fused_stattn),
                            hipFuncAttributeMaxDynamicSharedMemorySize, LDS_TOTAL);
  hipLaunchKernelGGL(pack_weights, dim3(16), dim3(256), 0, stream, Wq, Wkv, Wo, wsf);
  hipLaunchKernelGGL(fused_stattn, dim3(256), dim3(256), LDS_TOTAL, stream,
                     x, wsf, bo, pe, out);
}

// Round 13
// 214.238 us; speedup vs baseline: 1.4071x; 1.0758x over previous
//
#include <hip/hip_runtime.h>
#include <hip/hip_bf16.h>

typedef float  f32x4  __attribute__((ext_vector_type(4)));
typedef __bf16 bf16x8 __attribute__((ext_vector_type(8)));

#define SCALE_QK 0.17677669529663687f  /* 32^-0.5 (reference uses DIM_HEAD) */

// B=131072, L=4, dim=256, inner=32, heads=4, dh=8
// rows = 524288 ; 16-row tiles = 32768
// grid 1024 x 3 waves; slot = bid*3+wv; tiles strided by 3072 (10-11/wave)
// JOURNAL:
//  - VGPR cap law: cap = 256/(2nd launch_bounds arg); exceed -> spill.
//  - vmcnt in-order: per-tile vmem must be x-stage + out-stores ONLY.
//  - r11: NT loads/stores regressed (lost L3 residency).
//  - r12: contiguous-transaction theory NULL (230 == r9's 232, different
//    structure). Shared limiter = per-tile serialization (vmcnt(0) drain).
//  - r13: double-buffered stage + counted vmcnt(16) (T4 recipe): stage t+1
//    while computing t; D bounces through the just-consumed buffer.
//    3 waves/block (LDS 150.5KB), Wo frags in 64 regs, GEMM1 frags in LDS.

template<int CTRL>
__device__ __forceinline__ float dpp_add(float x) {
  int xi = __builtin_bit_cast(int, x);
  int yi = __builtin_amdgcn_mov_dpp(xi, CTRL, 0xF, 0xF, true);
  return x + __builtin_bit_cast(float, yi);
}

// ---------- prekernel: pack frag-ordered bf16 weights into d_ws ----------
// item = f*64 + lane, f in [0,64): wsf[item*8 + j]
// f in [0,48): GEMM1 frag (kt=f/6, ct=f%6): col n=ct*16+c, k=kt*32+g*8+j
// f in [48,64): Wo frag ct=f-48: col n=ct*16+c, k=g*8+j
__global__ void pack_weights(const float* __restrict__ Wq, const float* __restrict__ Wkv,
                             const float* __restrict__ Wo, __bf16* __restrict__ wsf) {
  const int item = blockIdx.x * 256 + threadIdx.x;   // 4096 items
  const int f = item >> 6, lane = item & 63;
  const int g = lane >> 4, c = lane & 15;
  union { bf16x8 v; __bf16 h[8]; } vv;
  if (f < 48) {
    const int kt = f / 6, ct = f - kt * 6;
    const int n = ct * 16 + c;
    #pragma unroll
    for (int j = 0; j < 8; ++j) {
      const int k = kt * 32 + g * 8 + j;
      vv.h[j] = (__bf16)((n < 32) ? Wq[k * 32 + n] : Wkv[k * 64 + (n - 32)]);
    }
  } else {
    const int ct = f - 48;
    const int n = ct * 16 + c;
    #pragma unroll
    for (int j = 0; j < 8; ++j) vv.h[j] = (__bf16)Wo[(g * 8 + j) * 256 + n];
  }
  *(bf16x8*)&wsf[item * 8] = vv.v;
}

#define FR1(f) (*(const bf16x8*)&wfrag1[(f) * 512 + lane * 8])
#define MFMA(a, b, cc) __builtin_amdgcn_mfma_f32_16x16x32_bf16((a), (b), (cc), 0, 0, 0)

// LDS map (bytes):
//   [0, 49152)        wfrag1 (GEMM1 frags 0..47): f*1024 + lane*16
//   [49152, 148992)   stage: wave wv, buf b at 49152 + wv*33280 + b*16640;
//                     row r at +r*1040 (1KB row + 16B pad)
//   [148992, 152832)  ao bounce: wave wv at +wv*1280 ([16][40] bf16)
//   [152832, 153856)  bo (256 f32)
//   [153856, 154112)  pe (64 f32)
#define LDS_TOTAL 154112

__global__ __launch_bounds__(192, 1) void fused_stattn(
    const float* __restrict__ x, const __bf16* __restrict__ wsf,
    const float* __restrict__ bo, const float* __restrict__ pe,
    float* __restrict__ out) {
  extern __shared__ char smem[];

  const int tid  = threadIdx.x;
  const int lane = tid & 63;
  const int wv   = tid >> 6;    // 0..2
  const int g    = lane >> 4;   // 16-lane group
  const int c    = lane & 15;   // col within fragment / A-row

  __bf16* wfrag1 = (__bf16*)smem;
  char*   stg0   = smem + 49152 + wv * 33280;          // wave-private dbuf base
  __bf16* aoW    = (__bf16*)(smem + 148992 + wv * 1280);
  float*  bo_l   = (float*)(smem + 152832);
  float*  pe_l   = (float*)(smem + 153856);

  // ---- Wo frags -> 64 regs. Issued FIRST: oldest in vmcnt queue, so the
  //      first in-loop vmcnt(16) drains them before any GEMM2 use. ----
  bf16x8 wo[16];
  #pragma unroll
  for (int i = 0; i < 16; ++i)
    wo[i] = *(const bf16x8*)&wsf[((48 + i) * 64 + lane) * 8];

  // ---- GEMM1 frags + bo + pe -> LDS ----
  #pragma unroll
  for (int it = 0; it < 16; ++it) {
    const int idx = it * 192 + tid;                    // 3072 x 16B chunks
    *(bf16x8*)&wfrag1[idx * 8] = *(const bf16x8*)&wsf[idx * 8];
  }
  bo_l[tid] = bo[tid];
  if (tid < 64) bo_l[192 + tid] = bo[192 + tid];
  if (tid < 64) pe_l[tid] = pe[tid];
  __syncthreads();

  const unsigned stg_lds = (unsigned)(unsigned long long)(void*)stg0;

  // stage one 16x256 f32 tile: 16 instrs, each 64 lanes x 16B = contiguous 1KB
  auto stage_tile = [&](unsigned dbase, int tile) {
    const float* src = x + (size_t)tile * 4096 + (lane << 2);
    #pragma unroll
    for (int r = 0; r < 16; ++r) {
      __builtin_amdgcn_global_load_lds(
          (const __attribute__((address_space(1))) void*)(src + r * 256),
          (__attribute__((address_space(3))) void*)(unsigned long long)(dbase + r * 1040),
          16, 0, 0);
    }
  };

  const int slot = blockIdx.x * 3 + wv;    // 0..3071
  int cur = 0;
  stage_tile(stg_lds, slot);               // prologue: first tile -> buf0

  for (int tile = slot; tile < 32768; tile += 3072) {
    const int nt = tile + 3072;
    // stores(prev) ds_reads must retire before overwriting buf cur^1
    asm volatile("s_waitcnt lgkmcnt(0)" ::: "memory");
    if (nt < 32768) stage_tile(stg_lds + (unsigned)((cur ^ 1) * 16640), nt);
    // counted wait: drains loads(tile) [+ older stores]; next-tile loads fly
    asm volatile("s_waitcnt vmcnt(16)" ::: "memory");
    __builtin_amdgcn_sched_barrier(0);     // rule 18: pin ds_reads below wait

    char* stg = stg0 + cur * 16640;

    // ---- GEMM1: x[16x256] @ Wqkv[256x96]; A-frags from LDS stage ----
    f32x4 acc0 = {0,0,0,0}, acc1 = {0,0,0,0}, acc2 = {0,0,0,0};
    f32x4 acc3 = {0,0,0,0}, acc4 = {0,0,0,0}, acc5 = {0,0,0,0};
    #pragma unroll
    for (int kt = 0; kt < 8; ++kt) {
      const f32x4 va = *(const f32x4*)(stg + c * 1040 + kt * 128 + g * 32);
      const f32x4 vb = *(const f32x4*)(stg + c * 1040 + kt * 128 + g * 32 + 16);
      union { bf16x8 v; __bf16 h[8]; } af;    // A-frag: row=c, k = kt*32 + g*8 + j
      #pragma unroll
      for (int j = 0; j < 4; ++j) { af.h[j] = (__bf16)va[j]; af.h[4+j] = (__bf16)vb[j]; }
      acc0 = MFMA(af.v, FR1(kt*6+0), acc0);
      acc1 = MFMA(af.v, FR1(kt*6+1), acc1);
      acc2 = MFMA(af.v, FR1(kt*6+2), acc2);
      acc3 = MFMA(af.v, FR1(kt*6+3), acc3);
      acc4 = MFMA(af.v, FR1(kt*6+4), acc4);
      acc5 = MFMA(af.v, FR1(kt*6+5), acc5);
    }
    // C layout: lane(g,c) reg i -> row g*4+i (batch g, seq i), col c. q/k/v pairs.

    // ---- attention (in registers; 8-lane head-dim reduce via DPP) ----
    const int h0 = c >> 3;
    float ao0[4], ao1[4];
    #pragma unroll
    for (int p = 0; p < 2; ++p) {
      const f32x4 qa = p ? acc1 : acc0;
      const f32x4 ka = p ? acc3 : acc2;
      const f32x4 va = p ? acc5 : acc4;
      const int ph = 2 * p + h0;              // head owning cols p*16 + c
      float sim[4][4];
      #pragma unroll
      for (int i = 0; i < 4; ++i)
        #pragma unroll
        for (int j = 0; j < 4; ++j) {
          float pr = qa[i] * ka[j];
          pr = dpp_add<0xB1>(pr);             // quad_perm xor1
          pr = dpp_add<0x4E>(pr);             // quad_perm xor2
          pr = dpp_add<0x141>(pr);            // row_half_mirror
          sim[i][j] = pr * SCALE_QK + pe_l[ph * 16 + i * 4 + j];
        }
      #pragma unroll
      for (int i = 0; i < 4; ++i) {
        const float m = fmaxf(fmaxf(sim[i][0], sim[i][1]), fmaxf(sim[i][2], sim[i][3]));
        const float e0 = __expf(sim[i][0] - m), e1 = __expf(sim[i][1] - m);
        const float e2 = __expf(sim[i][2] - m), e3 = __expf(sim[i][3] - m);
        const float rs = 1.0f / (e0 + e1 + e2 + e3);
        const float o  = (e0*va[0] + e1*va[1] + e2*va[2] + e3*va[3]) * rs;
        if (p) ao1[i] = o; else ao0[i] = o;
      }
    }

    // ---- bounce C-layout -> B-frag layout for GEMM2 (per-wave private) ----
    #pragma unroll
    for (int i = 0; i < 4; ++i) {
      aoW[(g*4 + i) * 40 + c]      = (__bf16)ao0[i];
      aoW[(g*4 + i) * 40 + 16 + c] = (__bf16)ao1[i];
    }
    const bf16x8 a2 = *(const bf16x8*)&aoW[c * 40 + g * 8];  // col=c(=x-row), k=g*8+j

    // ---- GEMM2 (swapped): Wo^T @ ao^T, bias as C-input; D -> consumed stage buf ----
    #pragma unroll
    for (int ct = 0; ct < 16; ++ct) {
      const f32x4 bv = *(const f32x4*)&bo_l[ct * 16 + g * 4];
      f32x4 o = MFMA(wo[ct], a2, bv);
      // D: lane(g,c) reg i -> out row c, col ct*16 + g*4 + i
      *(f32x4*)(stg + c * 1040 + ct * 64 + g * 16) = o;
    }

    // ---- contiguous stores: row r = 64 lanes x 16B = 1KB per instr ----
    {
      float* orow = out + (size_t)tile * 4096 + (lane << 2);
      #pragma unroll
      for (int r = 0; r < 16; ++r) {
        const f32x4 v = *(const f32x4*)(stg + r * 1040 + lane * 16);
        *(f32x4*)(orow + r * 256) = v;
      }
    }

    cur ^= 1;
  }
}

extern "C" void kernel_launch(void* const* d_in, const int* in_sizes, int n_in,
                              void* d_out, int out_size, void* d_ws, size_t ws_size,
                              hipStream_t stream) {
  const float* x   = (const float*)d_in[0];
  const float* Wq  = (const float*)d_in[1];
  const float* Wkv = (const float*)d_in[2];
  const float* Wo  = (const float*)d_in[3];
  const float* bo  = (const float*)d_in[4];
  const float* pe  = (const float*)d_in[5];
  float* out = (float*)d_out;
  __bf16* wsf = (__bf16*)d_ws;   // 64 KiB of frag-ordered bf16 weights

  (void)hipFuncSetAttribute(reinterpret_cast<const void*>(fused_stattn),
                            hipFuncAttributeMaxDynamicSharedMemorySize, LDS_TOTAL);
  hipLaunchKernelGGL(pack_weights, dim3(16), dim3(256), 0, stream, Wq, Wkv, Wo, wsf);
  hipLaunchKernelGGL(fused_stattn, dim3(1024), dim3(192), LDS_TOTAL, stream,
                     x, wsf, bo, pe, out);
}